// Round 20
// baseline (49.823 us; speedup 1.0000x reference)
//
#include <hip/hip_runtime.h>

// GaussianAntecedent: out[n,r] = mem[n,r] / (sum_r mem[n,r] + 1e-8)
// mem = exp2( -sum_d clamp(q*x+pn, +-K)^2 ),  K = sqrt(-log2(1e-8))
//   q = sqrt(0.5*log2 e)/(sigma+eps), pn = -c*q
//
// R19 post-mortem: s_load constants entangled with ds_write on lgkmcnt +
// 4-op/elem form -> regressed; transport conclusion stands (LDS pipe
// serves 256 uniform ds_read_b128/wave x ~12cy = 15.6us/CU floor in R16).
// R20: constants via uniform VECTOR global loads: pointer pinned into
// VGPRs (asm "+v") so the compiler must emit global_load_dwordx4 --
// single 16B L1-broadcast per instr, vmcnt-counted (disjoint from the
// memL ds_writes), deeply pipelined, 16KB table L1-resident.
// Everything else byte-identical to R16; tabL LDS deleted (52.7->36.4KB).

typedef float v2f __attribute__((ext_vector_type(2)));

constexpr int DDIM = 32;
constexpr int RR   = 64;
constexpr int ROWS = 128;         // rows per block (2 per lane)
constexpr int MP   = 130;         // mem tile pitch (floats)
constexpr int PP   = 5;           // partials pitch

__device__ inline float fast_exp2(float x) {
#if __has_builtin(__builtin_amdgcn_exp2f)
    return __builtin_amdgcn_exp2f(x);
#else
    return exp2f(x);
#endif
}

// ---- setup: per-rule table [ q[0..31] | pn[0..31] ] (64 floats/rule) ----
__global__ void gauss_setup_kernel(const float* __restrict__ centers,
                                   const float* __restrict__ sigma,
                                   float* __restrict__ ws) {
    const float SQK = 0.84932180028801907f;   // sqrt(0.5 * log2(e))
    int idx = blockIdx.x * blockDim.x + threadIdx.x;
    if (idx < RR * DDIM) {
        int r = idx >> 5, d = idx & 31;
        float q = SQK / (sigma[r * DDIM + d] + 1e-8f);
        ws[r * 64 + d]        = q;
        ws[r * 64 + DDIM + d] = -centers[r * DDIM + d] * q;
    }
}

__global__ __launch_bounds__(256, 3) void gauss_main(
    const float* __restrict__ X,
    const float* __restrict__ tab,    // d_ws: 64 rules x [q[32]|pn[32]]
    float* __restrict__ out, int N)
{
    __shared__ float memL[RR * MP];       // 33.3 KB [rule][row]
    __shared__ float partL[ROWS * PP];    // 2.56 KB [row][wave]
    __shared__ float rsL[ROWS];           // 0.5 KB  rcp(S) per row

    const int tid  = threadIdx.x;
    const int lane = tid & 63;
    const int w    = tid >> 6;
    const int n0   = blockIdx.x * ROWS;

    // ---- own rows -> VGPRs ----
    const int na = n0 + lane;
    const int nb = n0 + 64 + lane;
    const int ca = (na < N) ? na : (N - 1);
    const int cb = (nb < N) ? nb : (N - 1);
    const float4* __restrict__ xra =
        reinterpret_cast<const float4*>(X + (size_t)ca * DDIM);
    const float4* __restrict__ xrb =
        reinterpret_cast<const float4*>(X + (size_t)cb * DDIM);
    v2f xa2[16], xb2[16];
    #pragma unroll
    for (int j = 0; j < 8; ++j) {
        float4 va = xra[j], vb = xrb[j];
        xa2[2 * j]     = (v2f){va.x, va.y};
        xa2[2 * j + 1] = (v2f){va.z, va.w};
        xb2[2 * j]     = (v2f){vb.x, vb.y};
        xb2[2 * j + 1] = (v2f){vb.z, vb.w};
    }
    #pragma unroll
    for (int j = 0; j < 16; ++j) asm volatile("" : "+v"(xa2[j]), "+v"(xb2[j]));

    // ---- this wave's constant base, pinned into VGPRs: forces the
    // compiler to emit vector global_load_dwordx4 (uniform address ->
    // single 16B L1 broadcast; vmcnt-counted, pipelined) ----
    const float4* tq = reinterpret_cast<const float4*>(tab + (size_t)(w * 16) * 64);
    asm volatile("" : "+v"(tq));

    const float K = 5.1551357f;   // sqrt(26.575424759098897) = sqrt(-log2 1e-8)
    float Sa = 0.f, Sb = 0.f;

    // ---- 16 rules for this wave; both rows per constant read ----
    #pragma unroll
    for (int rr = 0; rr < 16; ++rr) {
        const int r = w * 16 + rr;
        const float4* __restrict__ tp = tq + rr * 16;  // 16 float4 per rule

        v2f Aa[2] = {{0.f,0.f},{0.f,0.f}};
        v2f Ab[2] = {{0.f,0.f},{0.f,0.f}};
        #pragma unroll
        for (int j = 0; j < 8; ++j) {
            float4 qf = tp[j];        // q  dims 4j..4j+3 (uniform L1 bcast)
            float4 pf = tp[8 + j];    // pn dims 4j..4j+3
            v2f q0 = {qf.x, qf.y}, q1 = {qf.z, qf.w};
            v2f p0 = {pf.x, pf.y}, p1 = {pf.z, pf.w};
            v2f ta0 = __builtin_elementwise_fma(q0, xa2[2*j],   p0);
            v2f ta1 = __builtin_elementwise_fma(q1, xa2[2*j+1], p1);
            v2f tb0 = __builtin_elementwise_fma(q0, xb2[2*j],   p0);
            v2f tb1 = __builtin_elementwise_fma(q1, xb2[2*j+1], p1);
            // clamp to [-K, K]: fminf(fmaxf(.)) fuses to v_med3_f32
            ta0.x = fminf(fmaxf(ta0.x, -K), K); ta0.y = fminf(fmaxf(ta0.y, -K), K);
            ta1.x = fminf(fmaxf(ta1.x, -K), K); ta1.y = fminf(fmaxf(ta1.y, -K), K);
            tb0.x = fminf(fmaxf(tb0.x, -K), K); tb0.y = fminf(fmaxf(tb0.y, -K), K);
            tb1.x = fminf(fmaxf(tb1.x, -K), K); tb1.y = fminf(fmaxf(tb1.y, -K), K);
            Aa[0] = __builtin_elementwise_fma(ta0, -ta0, Aa[0]);
            Aa[1] = __builtin_elementwise_fma(ta1, -ta1, Aa[1]);
            Ab[0] = __builtin_elementwise_fma(tb0, -tb0, Ab[0]);
            Ab[1] = __builtin_elementwise_fma(tb1, -tb1, Ab[1]);
        }
        v2f aa = Aa[0] + Aa[1];
        v2f ab = Ab[0] + Ab[1];
        float ma = fast_exp2(aa.x + aa.y);
        float mb = fast_exp2(ab.x + ab.y);
        Sa += ma;
        Sb += mb;
        memL[r * MP + lane]      = ma;   // stride-1 across lanes: clean
        memL[r * MP + 64 + lane] = mb;
    }
    partL[lane * PP + w]        = Sa;    // (5*lane+w)%32: 2-way, free
    partL[(64 + lane) * PP + w] = Sb;

    __syncthreads();   // mem tile + partials ready

    if (tid < ROWS) {
        float s = partL[tid * PP + 0] + partL[tid * PP + 1] +
                  partL[tid * PP + 2] + partL[tid * PP + 3];
        rsL[tid] = __builtin_amdgcn_rcpf(s + 1e-8f);
    }
    __syncthreads();   // rs ready

    // ---- epilogue: contiguous 4KB-per-step float4 stores ----
    const int nvalid = N - n0;   // rows in this block (128 except last)
    #pragma unroll
    for (int ch = 0; ch < 8; ++ch) {
        const int f4  = ch * 256 + tid;       // 0..2047
        const int row = f4 >> 4;              // 0..127
        const int r4  = (f4 & 15) * 4;        // rule quad base
        if (row < nvalid) {
            float rs = rsL[row];
            float4 o;
            o.x = memL[(r4 + 0) * MP + row] * rs;
            o.y = memL[(r4 + 1) * MP + row] * rs;
            o.z = memL[(r4 + 2) * MP + row] * rs;
            o.w = memL[(r4 + 3) * MP + row] * rs;
            *reinterpret_cast<float4*>(&out[(size_t)(n0 + row) * RR + r4]) = o;
        }
    }
}

extern "C" void kernel_launch(void* const* d_in, const int* in_sizes, int n_in,
                              void* d_out, int out_size, void* d_ws, size_t ws_size,
                              hipStream_t stream) {
    const float* X       = (const float*)d_in[0];
    const float* centers = (const float*)d_in[1];
    const float* sigma   = (const float*)d_in[2];
    float* out = (float*)d_out;
    float* ws  = (float*)d_ws;   // needs 64*64*4 = 16 KB

    const int N = in_sizes[0] / DDIM;  // 100000

    // 1) build per-rule q/pn table (2048 elems)
    gauss_setup_kernel<<<8, 256, 0, stream>>>(centers, sigma, ws);

    // 2) main: 782 blocks x 256 threads (128 rows/block, rules split 4 ways)
    const int grid = (N + ROWS - 1) / ROWS;   // 782
    gauss_main<<<grid, 256, 0, stream>>>(X, ws, out, N);
}

// Round 21
// 29.957 us; speedup vs baseline: 1.6632x; 1.6632x over previous
//
#include <hip/hip_runtime.h>

// GaussianAntecedent: out[n,r] = mem[n,r] / (sum_r mem[n,r] + 1e-8)
// mem = exp2( -sum_d clamp(q*x+pn, +-K)^2 ),  K = sqrt(-log2(1e-8))
//   q = sqrt(0.5*log2 e)/(sigma+eps), pn = -c*q
//
// R20 post-mortem (first main-kernel counters): VGPR_Count=52 < the 64
// needed for xa2/xb2 -> the "pinned" X was being SPILLED and RELOADED
// from L1 inside the rule loop (decl-point asm pin doesn't survive
// regalloc). 256 latency-exposed reloads/wave, in EVERY design -- the
// transport-independent basin. R21 = R16 + re-pin X at the top of every
// rule iteration (makes spill-reload unprofitable; X stays register-
// resident). Everything else byte-identical to R16 (30.0us best).

typedef float v2f __attribute__((ext_vector_type(2)));

constexpr int DDIM = 32;
constexpr int RR   = 64;
constexpr int ROWS = 128;         // rows per block (2 per lane)
constexpr int MP   = 130;         // mem tile pitch (floats)
constexpr int PP   = 5;           // partials pitch

__device__ inline float fast_exp2(float x) {
#if __has_builtin(__builtin_amdgcn_exp2f)
    return __builtin_amdgcn_exp2f(x);
#else
    return exp2f(x);
#endif
}

__global__ __launch_bounds__(256, 2) void gauss_main(
    const float* __restrict__ X,
    const float* __restrict__ centers,
    const float* __restrict__ sigma,
    float* __restrict__ out, int N)
{
    __shared__ float tabL[RR * 64];       // 16 KB  [rule]{q[32]|pn[32]}
    __shared__ float memL[RR * MP];       // 33.3 KB [rule][row]
    __shared__ float partL[ROWS * PP];    // 2.56 KB [row][wave]
    __shared__ float rsL[ROWS];           // 0.5 KB  rcp(S) per row

    const int tid  = threadIdx.x;
    const int lane = tid & 63;
    const int w    = tid >> 6;
    const int n0   = blockIdx.x * ROWS;

    // ---- own rows -> VGPRs (issued first; latency hides table build) ----
    const int na = n0 + lane;
    const int nb = n0 + 64 + lane;
    const int ca = (na < N) ? na : (N - 1);
    const int cb = (nb < N) ? nb : (N - 1);
    const float4* __restrict__ xra =
        reinterpret_cast<const float4*>(X + (size_t)ca * DDIM);
    const float4* __restrict__ xrb =
        reinterpret_cast<const float4*>(X + (size_t)cb * DDIM);
    v2f xa2[16], xb2[16];
    #pragma unroll
    for (int j = 0; j < 8; ++j) {
        float4 va = xra[j], vb = xrb[j];
        xa2[2 * j]     = (v2f){va.x, va.y};
        xa2[2 * j + 1] = (v2f){va.z, va.w};
        xb2[2 * j]     = (v2f){vb.x, vb.y};
        xb2[2 * j + 1] = (v2f){vb.z, vb.w};
    }

    // ---- build q/pn table in LDS (once per block; 8 divides/thread) ----
    const float SQK = 0.84932180028801907f;   // sqrt(0.5 * log2(e))
    #pragma unroll
    for (int i = 0; i < 8; ++i) {
        const int pi = tid * 8 + i;           // (rule, dim) pair 0..2047
        const int r  = pi >> 5, d = pi & 31;
        float q  = SQK / (sigma[r * DDIM + d] + 1e-8f);
        tabL[r * 64 + d]        = q;
        tabL[r * 64 + DDIM + d] = -centers[r * DDIM + d] * q;
    }

    __syncthreads();   // table ready

    const float K = 5.1551357f;   // sqrt(26.575424759098897) = sqrt(-log2 1e-8)
    float Sa = 0.f, Sb = 0.f;

    // ---- 16 rules for this wave; both rows per constant read ----
    #pragma unroll
    for (int rr = 0; rr < 16; ++rr) {
        // Re-pin X EVERY iteration: spill-reload is now unprofitable, the
        // allocator must keep all 64 X registers live across the loop.
        #pragma unroll
        for (int j = 0; j < 16; ++j)
            asm volatile("" : "+v"(xa2[j]), "+v"(xb2[j]));

        const int r = w * 16 + rr;
        const float4* __restrict__ tp =
            reinterpret_cast<const float4*>(&tabL[r * 64]);

        v2f Aa[2] = {{0.f,0.f},{0.f,0.f}};
        v2f Ab[2] = {{0.f,0.f},{0.f,0.f}};
        #pragma unroll
        for (int j = 0; j < 8; ++j) {
            float4 qf = tp[j];        // q  dims 4j..4j+3 (uniform broadcast)
            float4 pf = tp[8 + j];    // pn dims 4j..4j+3
            v2f q0 = {qf.x, qf.y}, q1 = {qf.z, qf.w};
            v2f p0 = {pf.x, pf.y}, p1 = {pf.z, pf.w};
            v2f ta0 = __builtin_elementwise_fma(q0, xa2[2*j],   p0);
            v2f ta1 = __builtin_elementwise_fma(q1, xa2[2*j+1], p1);
            v2f tb0 = __builtin_elementwise_fma(q0, xb2[2*j],   p0);
            v2f tb1 = __builtin_elementwise_fma(q1, xb2[2*j+1], p1);
            // clamp to [-K, K]: fminf(fmaxf(.)) fuses to v_med3_f32
            ta0.x = fminf(fmaxf(ta0.x, -K), K); ta0.y = fminf(fmaxf(ta0.y, -K), K);
            ta1.x = fminf(fmaxf(ta1.x, -K), K); ta1.y = fminf(fmaxf(ta1.y, -K), K);
            tb0.x = fminf(fmaxf(tb0.x, -K), K); tb0.y = fminf(fmaxf(tb0.y, -K), K);
            tb1.x = fminf(fmaxf(tb1.x, -K), K); tb1.y = fminf(fmaxf(tb1.y, -K), K);
            Aa[0] = __builtin_elementwise_fma(ta0, -ta0, Aa[0]);
            Aa[1] = __builtin_elementwise_fma(ta1, -ta1, Aa[1]);
            Ab[0] = __builtin_elementwise_fma(tb0, -tb0, Ab[0]);
            Ab[1] = __builtin_elementwise_fma(tb1, -tb1, Ab[1]);
        }
        v2f aa = Aa[0] + Aa[1];
        v2f ab = Ab[0] + Ab[1];
        float ma = fast_exp2(aa.x + aa.y);
        float mb = fast_exp2(ab.x + ab.y);
        Sa += ma;
        Sb += mb;
        memL[r * MP + lane]      = ma;   // stride-1 across lanes: clean
        memL[r * MP + 64 + lane] = mb;
    }
    partL[lane * PP + w]        = Sa;    // (5*lane+w)%32: 2-way, free
    partL[(64 + lane) * PP + w] = Sb;

    __syncthreads();   // mem tile + partials ready

    if (tid < ROWS) {
        float s = partL[tid * PP + 0] + partL[tid * PP + 1] +
                  partL[tid * PP + 2] + partL[tid * PP + 3];
        rsL[tid] = __builtin_amdgcn_rcpf(s + 1e-8f);
    }
    __syncthreads();   // rs ready

    // ---- epilogue: contiguous 4KB-per-step float4 stores ----
    const int nvalid = N - n0;   // rows in this block (128 except last)
    #pragma unroll
    for (int ch = 0; ch < 8; ++ch) {
        const int f4  = ch * 256 + tid;       // 0..2047
        const int row = f4 >> 4;              // 0..127
        const int r4  = (f4 & 15) * 4;        // rule quad base
        if (row < nvalid) {
            float rs = rsL[row];
            float4 o;
            o.x = memL[(r4 + 0) * MP + row] * rs;
            o.y = memL[(r4 + 1) * MP + row] * rs;
            o.z = memL[(r4 + 2) * MP + row] * rs;
            o.w = memL[(r4 + 3) * MP + row] * rs;
            *reinterpret_cast<float4*>(&out[(size_t)(n0 + row) * RR + r4]) = o;
        }
    }
}

extern "C" void kernel_launch(void* const* d_in, const int* in_sizes, int n_in,
                              void* d_out, int out_size, void* d_ws, size_t ws_size,
                              hipStream_t stream) {
    const float* X       = (const float*)d_in[0];
    const float* centers = (const float*)d_in[1];
    const float* sigma   = (const float*)d_in[2];
    float* out = (float*)d_out;

    const int N = in_sizes[0] / DDIM;  // 100000
    const int grid = (N + ROWS - 1) / ROWS;   // 782
    gauss_main<<<grid, 256, 0, stream>>>(X, centers, sigma, out, N);
}

// Round 23
// 29.413 us; speedup vs baseline: 1.6939x; 1.0185x over previous
//
#include <hip/hip_runtime.h>

// GaussianAntecedent: out[n,r] = mem[n,r] / (sum_r mem[n,r] + 1e-8)
// mem = exp2( -sum_d clamp(q*x+pn, +-K)^2 ),  K = sqrt(-log2(1e-8))
//   q = sqrt(0.5*log2 e)/(sigma+eps), pn = -c*q
//
// R22 post-mortem: compile error -- LLVM rejects 128-bit float4 as an
// asm "v" operand. Fix: pin via SCALAR components (input-only, no
// writeback copies). Theory unchanged from R22: R20's VGPR=52 shows the
// compiler serializes ds_read->use per rule; batch-loading all 16
// float4 + pin forces 64 live dest VGPRs -> one pipelined ds_read burst
// (~130cy/rule instead of ~1000cy). MP=131 kills the epilogue 4-way
// bank conflict (600K -> ~0).

typedef float v2f __attribute__((ext_vector_type(2)));

constexpr int DDIM = 32;
constexpr int RR   = 64;
constexpr int ROWS = 128;         // rows per block (2 per lane)
constexpr int MP   = 131;         // mem tile pitch (floats); 524%32=12
constexpr int PP   = 5;           // partials pitch

__device__ inline float fast_exp2(float x) {
#if __has_builtin(__builtin_amdgcn_exp2f)
    return __builtin_amdgcn_exp2f(x);
#else
    return exp2f(x);
#endif
}

__global__ __launch_bounds__(256, 2) void gauss_main(
    const float* __restrict__ X,
    const float* __restrict__ centers,
    const float* __restrict__ sigma,
    float* __restrict__ out, int N)
{
    __shared__ float tabL[RR * 64];       // 16 KB  [rule]{q[32]|pn[32]}
    __shared__ float memL[RR * MP];       // 33.5 KB [rule][row]
    __shared__ float partL[ROWS * PP];    // 2.56 KB [row][wave]
    __shared__ float rsL[ROWS];           // 0.5 KB  rcp(S) per row

    const int tid  = threadIdx.x;
    const int lane = tid & 63;
    const int w    = tid >> 6;
    const int n0   = blockIdx.x * ROWS;

    // ---- own rows -> VGPRs (issued first; latency hides table build) ----
    const int na = n0 + lane;
    const int nb = n0 + 64 + lane;
    const int ca = (na < N) ? na : (N - 1);
    const int cb = (nb < N) ? nb : (N - 1);
    const float4* __restrict__ xra =
        reinterpret_cast<const float4*>(X + (size_t)ca * DDIM);
    const float4* __restrict__ xrb =
        reinterpret_cast<const float4*>(X + (size_t)cb * DDIM);
    v2f xa2[16], xb2[16];
    #pragma unroll
    for (int j = 0; j < 8; ++j) {
        float4 va = xra[j], vb = xrb[j];
        xa2[2 * j]     = (v2f){va.x, va.y};
        xa2[2 * j + 1] = (v2f){va.z, va.w};
        xb2[2 * j]     = (v2f){vb.x, vb.y};
        xb2[2 * j + 1] = (v2f){vb.z, vb.w};
    }

    // ---- build q/pn table in LDS (once per block; 8 divides/thread) ----
    const float SQK = 0.84932180028801907f;   // sqrt(0.5 * log2(e))
    #pragma unroll
    for (int i = 0; i < 8; ++i) {
        const int pi = tid * 8 + i;           // (rule, dim) pair 0..2047
        const int r  = pi >> 5, d = pi & 31;
        float q  = SQK / (sigma[r * DDIM + d] + 1e-8f);
        tabL[r * 64 + d]        = q;
        tabL[r * 64 + DDIM + d] = -centers[r * DDIM + d] * q;
    }

    __syncthreads();   // table ready

    const float K = 5.1551357f;   // sqrt(26.575424759098897) = sqrt(-log2 1e-8)
    float Sa = 0.f, Sb = 0.f;

    // ---- 16 rules for this wave; batched constant loads per rule ----
    #pragma unroll
    for (int rr = 0; rr < 16; ++rr) {
        const int r = w * 16 + rr;
        const float4* __restrict__ tp =
            reinterpret_cast<const float4*>(&tabL[r * 64]);

        // Batch-load ALL 16 float4 of this rule, then pin each value with
        // a scalar input-only "v" (legal operand size; no writeback).
        // Forces the 16 ds_read_b128 to issue as one pipelined burst.
        float4 cf[16];
        #pragma unroll
        for (int j = 0; j < 16; ++j) cf[j] = tp[j];
        #pragma unroll
        for (int j = 0; j < 16; ++j)
            asm volatile("" :: "v"(cf[j].x), "v"(cf[j].y),
                               "v"(cf[j].z), "v"(cf[j].w));

        v2f Aa[2] = {{0.f,0.f},{0.f,0.f}};
        v2f Ab[2] = {{0.f,0.f},{0.f,0.f}};
        #pragma unroll
        for (int j = 0; j < 8; ++j) {
            float4 qf = cf[j];        // q  dims 4j..4j+3
            float4 pf = cf[8 + j];    // pn dims 4j..4j+3
            v2f q0 = {qf.x, qf.y}, q1 = {qf.z, qf.w};
            v2f p0 = {pf.x, pf.y}, p1 = {pf.z, pf.w};
            v2f ta0 = __builtin_elementwise_fma(q0, xa2[2*j],   p0);
            v2f ta1 = __builtin_elementwise_fma(q1, xa2[2*j+1], p1);
            v2f tb0 = __builtin_elementwise_fma(q0, xb2[2*j],   p0);
            v2f tb1 = __builtin_elementwise_fma(q1, xb2[2*j+1], p1);
            // clamp to [-K, K]: fminf(fmaxf(.)) fuses to v_med3_f32
            ta0.x = fminf(fmaxf(ta0.x, -K), K); ta0.y = fminf(fmaxf(ta0.y, -K), K);
            ta1.x = fminf(fmaxf(ta1.x, -K), K); ta1.y = fminf(fmaxf(ta1.y, -K), K);
            tb0.x = fminf(fmaxf(tb0.x, -K), K); tb0.y = fminf(fmaxf(tb0.y, -K), K);
            tb1.x = fminf(fmaxf(tb1.x, -K), K); tb1.y = fminf(fmaxf(tb1.y, -K), K);
            Aa[0] = __builtin_elementwise_fma(ta0, -ta0, Aa[0]);
            Aa[1] = __builtin_elementwise_fma(ta1, -ta1, Aa[1]);
            Ab[0] = __builtin_elementwise_fma(tb0, -tb0, Ab[0]);
            Ab[1] = __builtin_elementwise_fma(tb1, -tb1, Ab[1]);
        }
        v2f aa = Aa[0] + Aa[1];
        v2f ab = Ab[0] + Ab[1];
        float ma = fast_exp2(aa.x + aa.y);
        float mb = fast_exp2(ab.x + ab.y);
        Sa += ma;
        Sb += mb;
        memL[r * MP + lane]      = ma;   // stride-1 across lanes: clean
        memL[r * MP + 64 + lane] = mb;
    }
    partL[lane * PP + w]        = Sa;    // (5*lane+w)%32: 2-way, free
    partL[(64 + lane) * PP + w] = Sb;

    __syncthreads();   // mem tile + partials ready

    if (tid < ROWS) {
        float s = partL[tid * PP + 0] + partL[tid * PP + 1] +
                  partL[tid * PP + 2] + partL[tid * PP + 3];
        rsL[tid] = __builtin_amdgcn_rcpf(s + 1e-8f);
    }
    __syncthreads();   // rs ready

    // ---- epilogue: contiguous 4KB-per-step float4 stores ----
    const int nvalid = N - n0;   // rows in this block (128 except last)
    #pragma unroll
    for (int ch = 0; ch < 8; ++ch) {
        const int f4  = ch * 256 + tid;       // 0..2047
        const int row = f4 >> 4;              // 0..127
        const int r4  = (f4 & 15) * 4;        // rule quad base
        if (row < nvalid) {
            float rs = rsL[row];
            float4 o;
            o.x = memL[(r4 + 0) * MP + row] * rs;
            o.y = memL[(r4 + 1) * MP + row] * rs;
            o.z = memL[(r4 + 2) * MP + row] * rs;
            o.w = memL[(r4 + 3) * MP + row] * rs;
            *reinterpret_cast<float4*>(&out[(size_t)(n0 + row) * RR + r4]) = o;
        }
    }
}

extern "C" void kernel_launch(void* const* d_in, const int* in_sizes, int n_in,
                              void* d_out, int out_size, void* d_ws, size_t ws_size,
                              hipStream_t stream) {
    const float* X       = (const float*)d_in[0];
    const float* centers = (const float*)d_in[1];
    const float* sigma   = (const float*)d_in[2];
    float* out = (float*)d_out;

    const int N = in_sizes[0] / DDIM;  // 100000
    const int grid = (N + ROWS - 1) / ROWS;   // 782
    gauss_main<<<grid, 256, 0, stream>>>(X, centers, sigma, out, N);
}